// Round 9
// baseline (40.996 us; speedup 1.0000x reference)
//
#include <hip/hip_runtime.h>
#include <hip/hip_bf16.h>

#define OUT_N 8192
#define IN_N  8192
#define QROW  (IN_N / 2)     // 4096 int32 per out row (one widened byte each)
#define NCH   8              // k sub-chunks per wave
#define CH32  64             // int32 per row per sub-chunk (per wave)

typedef __attribute__((ext_vector_type(8))) short short8v;  // 8 bf16
typedef __attribute__((ext_vector_type(4))) float f32x4;

__device__ __forceinline__ unsigned int bf16pk(float a, float b) {
    __hip_bfloat162 h = __float22bfloat162_rn(make_float2(a, b));
    unsigned int u;
    __builtin_memcpy(&u, &h, 4);
    return u;
}

// async global->LDS, 16B/lane; LDS dest = wave-uniform base + lane*16 (HW rule)
__device__ __forceinline__ void gld_lds16(const int* gsrc, int* ldst_base) {
    __builtin_amdgcn_global_load_lds(
        (const __attribute__((address_space(1))) void*)gsrc,
        (__attribute__((address_space(3))) void*)ldst_base, 16, 0, 0);
}

#define SCHED0() __builtin_amdgcn_sched_barrier(0)

// R6 wave-private skeleton + spill-free fused x conversion.
// One block = one 16-out-row tile; 8 waves split K 8 ways; each wave DMAs the
// exact 4KB q-slice it consumes into its own LDS double buffer (no block
// barrier in the main loop). Counted vmcnt ledger per chunk:
//   issue x(c+1) fp32 [8] -> issue q(c+1) DMA [4] -> vmcnt(12) [q(c) ready]
//   -> compute c -> vmcnt(4) [x(c+1) ready, q(c+1) in flight] -> convert.
// x-path registers: xf 32 + xcur 16 VGPRs (R8's spill was 128).
// LDS read swizzle: slot j of row R stored at j^R via pre-swizzled DMA source.
__global__ __launch_bounds__(512, 4) void qlin_mfma_kernel(
    const int*   __restrict__ qp,
    const float* __restrict__ x,
    const float* __restrict__ scale,
    const float* __restrict__ bias,
    float*       __restrict__ out)
{
    __shared__ int   qbuf[8][2][16 * CH32];   // 8 waves x 2 x 4KB = 64 KB
    __shared__ float red[8][16][17];          // 8.7 KB reduction scratch

    const int t = threadIdx.x;
    const int w = t >> 6;            // wave id -> k range [w*1024, +1024) elems
    const int l = t & 63;
    const int g = l >> 4;            // lane group 0..3
    const int r = l & 15;            // A: batch row, B: out row within tile
    const int tile = blockIdx.x;
    const int obase = tile * 16;

    const int* qwbase = qp + (size_t)obase * QROW + w * (QROW / 8);
    const int drow = l >> 4;                      // DMA row sub-index (+4p)
    // x fp32: elem = r*IN_N + w*1024 + c*128 + s*32 + g*8
    const float* xwbase = x + (size_t)r * IN_N + w * (IN_N / 8) + g * 8;

    f32x4 acc = {0.f, 0.f, 0.f, 0.f};
    float4 xf[4][2];      // fp32 staging for next chunk (32 VGPRs)
    uint4  xcur[4];       // converted bf16 fragments for current chunk (16)

#define ISSUE_X(c_)                                                       \
    do { _Pragma("unroll")                                                \
        for (int s = 0; s < 4; ++s) {                                     \
            xf[s][0] = *(const float4*)(xwbase + (c_) * 128 + s * 32);    \
            xf[s][1] = *(const float4*)(xwbase + (c_) * 128 + s * 32 + 4);\
        } } while (0)

#define ISSUE_Q(c_)                                                       \
    do { _Pragma("unroll")                                                \
        for (int p = 0; p < 4; ++p) {                                     \
            const int row = 4 * p + drow;                                 \
            const int j   = (l & 15) ^ (row & 15);                        \
            gld_lds16(qwbase + (size_t)row * QROW + (c_) * CH32 + j * 4,  \
                      &qbuf[w][(c_) & 1][p * 256]);                       \
        } } while (0)

#define CONVERT_X()                                                       \
    do { _Pragma("unroll")                                                \
        for (int s = 0; s < 4; ++s) {                                     \
            xcur[s].x = bf16pk(xf[s][0].x, xf[s][0].y);                   \
            xcur[s].y = bf16pk(xf[s][0].z, xf[s][0].w);                   \
            xcur[s].z = bf16pk(xf[s][1].x, xf[s][1].y);                   \
            xcur[s].w = bf16pk(xf[s][1].z, xf[s][1].w);                   \
        } } while (0)

    // ---- prologue: x(0), q(0); convert x(0) (q(0)'s 4 DMAs stay in flight)
    ISSUE_X(0);
    SCHED0();
    ISSUE_Q(0);
    SCHED0();
    asm volatile("s_waitcnt vmcnt(4)" ::: "memory");
    SCHED0();
    CONVERT_X();

    #pragma unroll   // full unroll: static buffer indices + static vmcnt imms
    for (int c = 0; c < NCH; ++c) {
        const int cur = c & 1;

        if (c + 1 < NCH) {
            ISSUE_X(c + 1);          // 8 vmem (L2-hot fp32 x)
            SCHED0();
            ISSUE_Q(c + 1);          // 4 vmem (HBM q DMA)
            SCHED0();
            // retire q(c) [oldest 4]; keep x(c+1)+q(c+1)=12 in flight
            asm volatile("s_waitcnt vmcnt(12)" ::: "memory");
        } else {
            asm volatile("s_waitcnt vmcnt(0)" ::: "memory");
        }
        SCHED0();                    // rule #18: pin ds_reads below the wait

        const char* wb = (const char*)qbuf[w][cur];
        #pragma unroll
        for (int s = 0; s < 4; ++s) {
            // read slot j0 = s*4+g of row r, stored at slot j0^r (2-way = free)
            const int4 q = *(const int4*)(wb + r * 256 + ((((s << 2) + g) ^ r) << 4));
            // nibble e=2m lo / e=2m+1 hi of byte m; signed; exact in bf16
            uint4 ub = {
                bf16pk((float)((q.x << 28) >> 28), (float)((q.x << 24) >> 28)),
                bf16pk((float)((q.y << 28) >> 28), (float)((q.y << 24) >> 28)),
                bf16pk((float)((q.z << 28) >> 28), (float)((q.z << 24) >> 28)),
                bf16pk((float)((q.w << 28) >> 28), (float)((q.w << 24) >> 28))
            };
            short8v bfrag = __builtin_bit_cast(short8v, ub);
            short8v afrag = __builtin_bit_cast(short8v, xcur[s]);
            acc = __builtin_amdgcn_mfma_f32_16x16x32_bf16(afrag, bfrag, acc, 0, 0, 0);
        }

        if (c + 1 < NCH) {
            SCHED0();
            // x(c+1) has long arrived (issued ~6000 cyc ago); q(c+1) in flight
            asm volatile("s_waitcnt vmcnt(4)" ::: "memory");
            SCHED0();
            CONVERT_X();             // xf -> xcur for chunk c+1 (16 cvt_pk)
        }
    }
#undef ISSUE_X
#undef ISSUE_Q
#undef CONVERT_X

    // ---- cross-wave K reduction; D map: col=lane&15 (out), row=(lane>>4)*4+j
    red[w][g * 4 + 0][r] = acc[0];
    red[w][g * 4 + 1][r] = acc[1];
    red[w][g * 4 + 2][r] = acc[2];
    red[w][g * 4 + 3][r] = acc[3];
    __syncthreads();

    if (t < 256) {
        const int b = t >> 4;            // batch
        const int o = t & 15;            // out within tile
        const int oc = obase + o;
        float v = 0.f;
        #pragma unroll
        for (int i = 0; i < 8; ++i) v += red[i][b][o];
        out[b * OUT_N + oc] = v * scale[oc >> 7] + bias[oc];
    }
}

extern "C" void kernel_launch(void* const* d_in, const int* in_sizes, int n_in,
                              void* d_out, int out_size, void* d_ws, size_t ws_size,
                              hipStream_t stream) {
    (void)in_sizes; (void)n_in; (void)d_ws; (void)ws_size; (void)out_size;
    const float* x     = (const float*)d_in[0];
    const int*   qp    = (const int*)d_in[1];
    const float* scale = (const float*)d_in[2];
    const float* bias  = (const float*)d_in[3];
    float*       out   = (float*)d_out;

    qlin_mfma_kernel<<<dim3(OUT_N / 16), dim3(512), 0, stream>>>(qp, x, scale, bias, out);
}

// Round 10
// 36.659 us; speedup vs baseline: 1.1183x; 1.1183x over previous
//
#include <hip/hip_runtime.h>
#include <hip/hip_bf16.h>

#define OUT_N 8192
#define IN_N  8192
#define QROW  (IN_N / 2)     // 4096 int32 per out row (one widened byte each)
#define WAVES 4              // waves per block (k-split ways)
#define KPW   (IN_N / WAVES) // 2048 in-elems per wave
#define NCH   8              // k sub-chunks per wave
#define CH32  128            // int32 per row per chunk -> 512-B DRAM granule
#define STEPS 8              // MFMA k-steps per chunk (256 elems / 32)

typedef __attribute__((ext_vector_type(8))) short short8v;  // 8 bf16
typedef __attribute__((ext_vector_type(4))) float f32x4;

__device__ __forceinline__ unsigned int bf16pk(float a, float b) {
    __hip_bfloat162 h = __float22bfloat162_rn(make_float2(a, b));
    unsigned int u;
    __builtin_memcpy(&u, &h, 4);
    return u;
}

// async global->LDS, 16B/lane; LDS dest = wave-uniform base + lane*16 (HW rule)
__device__ __forceinline__ void gld_lds16(const int* gsrc, int* ldst_base) {
    __builtin_amdgcn_global_load_lds(
        (const __attribute__((address_space(1))) void*)gsrc,
        (__attribute__((address_space(3))) void*)ldst_base, 16, 0, 0);
}

#define SCHED0() __builtin_amdgcn_sched_barrier(0)

// Pre-pass: x fp32 -> bf16 row-major [16][8192] in d_ws (256 KB, L2/L3-hot).
__global__ __launch_bounds__(256) void xconv_kernel(
    const float* __restrict__ x, unsigned short* __restrict__ xb)
{
    int i = (blockIdx.x * 256 + threadIdx.x) * 4;
    float4 v = *(const float4*)(x + i);
    uint2 u = { bf16pk(v.x, v.y), bf16pk(v.z, v.w) };
    *(uint2*)(xb + i) = u;
}

// R6 engine with 512-B DRAM granules. One block = one 16-out-row tile; 4 waves
// split K 4 ways; each wave DMAs the exact 8KB q-slice it consumes per chunk
// (16 rows x 512 B) into its own LDS double buffer via 8 x 1KB contiguous
// DMAs (2 rows x 512 B each). No block barrier in the main loop; counted
// vmcnt(16) keeps chunk c+1's 16 vmem ops in flight, vmcnt(0) only last.
// Swizzle: logical 16B slot j of row R stored at physical j^(R&7) via
// pre-swizzled DMA source (LDS dest linear, m173); same involution on read.
__global__ __launch_bounds__(256, 2) void qlin_mfma_kernel(
    const int*            __restrict__ qp,
    const unsigned short* __restrict__ xb,
    const float*          __restrict__ scale,
    const float*          __restrict__ bias,
    float*                __restrict__ out)
{
    __shared__ int   qbuf[WAVES][2][16 * CH32];  // 4 waves x 2 x 8KB = 64 KB
    __shared__ float red[WAVES][16][17];         // 4.4 KB reduction scratch

    const int t = threadIdx.x;
    const int w = t >> 6;            // wave id -> k range [w*2048, +2048) elems
    const int l = t & 63;
    const int g = l >> 4;            // lane group 0..3
    const int r = l & 15;            // A: batch row, B: out row within tile
    const int tile = blockIdx.x;
    const int obase = tile * 16;

    // wave-uniform q base for this wave's k-range (int32 units)
    const int* qwbase = qp + (size_t)obase * QROW + w * (KPW / 2);
    const int dR = l >> 5;                        // DMA row sub-index (0/1)
    const int dslot = l & 31;                     // DMA 16B-slot within row
    // x bf16 base: elem = r*IN_N + w*KPW + c*256 + s*32 + g*8
    const unsigned short* xwbase = xb + (size_t)r * IN_N + w * KPW + g * 8;

    f32x4 acc = {0.f, 0.f, 0.f, 0.f};
    uint4 xr[2][STEPS];              // bf16 x fragments, double-buffered (64 VGPR)

    // 8 q-DMAs for chunk c_: instr p covers rows 2p,2p+1 (512 B contiguous/row)
#define ISSUE_Q(c_)                                                         \
    do { _Pragma("unroll")                                                  \
        for (int p = 0; p < 8; ++p) {                                       \
            const int R = 2 * p + dR;                                       \
            const int s_ = dslot ^ (R & 7);   /* pre-swizzled source slot */ \
            gld_lds16(qwbase + (size_t)R * QROW + (c_) * CH32 + s_ * 4,     \
                      &qbuf[w][(c_) & 1][(2 * p) * CH32]);                  \
        } } while (0)

#define ISSUE_X(c_)                                                         \
    do { _Pragma("unroll")                                                  \
        for (int s = 0; s < STEPS; ++s)                                     \
            xr[(c_) & 1][s] = *(const uint4*)(xwbase + (c_) * 256 + s * 32);\
        } while (0)

    // ---- prologue: chunk 0 (8 x-loads then 8 DMAs = 16 vmem ops)
    ISSUE_X(0);
    ISSUE_Q(0);

    #pragma unroll   // full unroll: static buffer indices + static vmcnt imms
    for (int c = 0; c < NCH; ++c) {
        const int cur = c & 1;

        if (c + 1 < NCH) {
            ISSUE_X(c + 1);          // 8 vmem (L2-hot bf16 x)
            ISSUE_Q(c + 1);          // 8 vmem (HBM q DMA, 512-B granules)
            // retire chunk c's 16 oldest; keep chunk c+1's 16 in flight
            asm volatile("s_waitcnt vmcnt(16)" ::: "memory");
        } else {
            asm volatile("s_waitcnt vmcnt(0)" ::: "memory");
        }
        SCHED0();                    // rule #18: pin ds_reads below the wait

        const char* wb = (const char*)&qbuf[w][cur][0];
        #pragma unroll
        for (int s = 0; s < STEPS; ++s) {
            // logical slot j = s*4+g of row r lives at physical j^(r&7)
            const int4 q = *(const int4*)(wb + r * 512 + ((((s << 2) + g) ^ (r & 7)) << 4));
            // nibble e=2m lo / e=2m+1 hi of byte m; signed; exact in bf16
            uint4 ub = {
                bf16pk((float)((q.x << 28) >> 28), (float)((q.x << 24) >> 28)),
                bf16pk((float)((q.y << 28) >> 28), (float)((q.y << 24) >> 28)),
                bf16pk((float)((q.z << 28) >> 28), (float)((q.z << 24) >> 28)),
                bf16pk((float)((q.w << 28) >> 28), (float)((q.w << 24) >> 28))
            };
            short8v bfrag = __builtin_bit_cast(short8v, ub);
            short8v afrag = __builtin_bit_cast(short8v, xr[cur][s]);
            acc = __builtin_amdgcn_mfma_f32_16x16x32_bf16(afrag, bfrag, acc, 0, 0, 0);
        }
    }
#undef ISSUE_Q
#undef ISSUE_X

    // ---- cross-wave K reduction; D map: col=lane&15 (out), row=(lane>>4)*4+j
    red[w][g * 4 + 0][r] = acc[0];
    red[w][g * 4 + 1][r] = acc[1];
    red[w][g * 4 + 2][r] = acc[2];
    red[w][g * 4 + 3][r] = acc[3];
    __syncthreads();

    {
        const int b = t >> 4;            // batch
        const int o = t & 15;            // out within tile
        const int oc = obase + o;
        float v = 0.f;
        #pragma unroll
        for (int i = 0; i < WAVES; ++i) v += red[i][b][o];
        out[b * OUT_N + oc] = v * scale[oc >> 7] + bias[oc];
    }
}

extern "C" void kernel_launch(void* const* d_in, const int* in_sizes, int n_in,
                              void* d_out, int out_size, void* d_ws, size_t ws_size,
                              hipStream_t stream) {
    (void)in_sizes; (void)n_in; (void)ws_size; (void)out_size;
    const float* x     = (const float*)d_in[0];
    const int*   qp    = (const int*)d_in[1];
    const float* scale = (const float*)d_in[2];
    const float* bias  = (const float*)d_in[3];
    float*       out   = (float*)d_out;
    unsigned short* xb = (unsigned short*)d_ws;    // 256 KB bf16 x

    xconv_kernel<<<dim3((16 * IN_N) / (256 * 4)), dim3(256), 0, stream>>>(x, xb);
    qlin_mfma_kernel<<<dim3(OUT_N / 16), dim3(256), 0, stream>>>(qp, xb, scale, bias, out);
}

// Round 11
// 36.043 us; speedup vs baseline: 1.1374x; 1.0171x over previous
//
#include <hip/hip_runtime.h>
#include <hip/hip_bf16.h>

#define OUT_N 8192
#define IN_N  8192
#define QROW  (IN_N / 2)     // 4096 int32 per out row (one widened byte each)
#define NCH   8              // k sub-chunks per wave
#define CH32  64             // int32 per row per sub-chunk (per wave)

typedef __attribute__((ext_vector_type(8))) short short8v;  // 8 bf16
typedef __attribute__((ext_vector_type(4))) float f32x4;

__device__ __forceinline__ unsigned int bf16pk(float a, float b) {
    __hip_bfloat162 h = __float22bfloat162_rn(make_float2(a, b));
    unsigned int u;
    __builtin_memcpy(&u, &h, 4);
    return u;
}

// async global->LDS, 16B/lane; LDS dest = wave-uniform base + lane*16 (HW rule)
// aux=2 -> NT (non-temporal / evict-first): q is streamed once, keep L2 for x
__device__ __forceinline__ void gld_lds16_nt(const int* gsrc, int* ldst_base) {
    __builtin_amdgcn_global_load_lds(
        (const __attribute__((address_space(1))) void*)gsrc,
        (__attribute__((address_space(3))) void*)ldst_base, 16, 0, 2);
}

// Pre-pass: x fp32 -> bf16 row-major [16][8192] in d_ws (256 KB, L2/L3-hot).
__global__ __launch_bounds__(256) void xconv_kernel(
    const float* __restrict__ x, unsigned short* __restrict__ xb)
{
    int i = (blockIdx.x * 256 + threadIdx.x) * 4;
    float4 v = *(const float4*)(x + i);
    uint2 u = { bf16pk(v.x, v.y), bf16pk(v.z, v.w) };
    *(uint2*)(xb + i) = u;
}

// R6 engine (proven 32.9 us) + NT policy on q DMAs.
// One block = one 16-out-row tile; 8 waves split K 8 ways. WAVE-PRIVATE q
// staging: each wave DMAs the exact 4KB slice it consumes (16 rows x 256B of
// its k-range) into its own LDS double buffer -> NO block barrier in the main
// loop; counted vmcnt(8) keeps next chunk's 8 vmem ops in flight (T4),
// vmcnt(0) only on the last chunk.
// LDS read swizzle: slot j of row R stored at j^R (global DMA source
// pre-swizzled, LDS dest linear — m173).
__global__ __launch_bounds__(512, 4) void qlin_mfma_kernel(
    const int*            __restrict__ qp,
    const unsigned short* __restrict__ xb,
    const float*          __restrict__ scale,
    const float*          __restrict__ bias,
    float*                __restrict__ out)
{
    __shared__ int   qbuf[8][2][16 * CH32];   // 8 waves x 2 x 4KB = 64 KB
    __shared__ float red[8][16][17];          // 8.7 KB reduction scratch

    const int t = threadIdx.x;
    const int w = t >> 6;            // wave id -> k range [w*1024, +1024) elems
    const int l = t & 63;
    const int g = l >> 4;            // lane group 0..3
    const int r = l & 15;            // A: batch row, B: out row within tile
    const int tile = blockIdx.x;
    const int obase = tile * 16;

    // wave-uniform q base for this wave's k-range (int32 units)
    const int* qwbase = qp + (size_t)obase * QROW + w * (QROW / 8);
    const int drow = l >> 4;                      // DMA row sub-index (+4p)
    // x bf16 base: elem = r*IN_N + w*1024 + c*128 + s*32 + g*8
    const unsigned short* xwbase = xb + (size_t)r * IN_N + w * (IN_N / 8) + g * 8;

    f32x4 acc = {0.f, 0.f, 0.f, 0.f};
    uint4 xr[2][4];

    // ---- prologue: chunk 0 (4 x-loads then 4 DMAs = 8 vmem ops)
    #pragma unroll
    for (int s = 0; s < 4; ++s)
        xr[0][s] = *(const uint4*)(xwbase + s * 32);
    #pragma unroll
    for (int p = 0; p < 4; ++p) {
        const int row = 4 * p + drow;
        const int j   = (l & 15) ^ (row & 15);    // pre-swizzled source slot
        gld_lds16_nt(qwbase + (size_t)row * QROW + j * 4, &qbuf[w][0][p * 256]);
    }

    #pragma unroll   // full unroll: static buffer indices + static vmcnt imms
    for (int c = 0; c < NCH; ++c) {
        const int cur = c & 1;

        if (c + 1 < NCH) {
            // issue next chunk: x loads FIRST (L2, retire first), then DMAs
            #pragma unroll
            for (int s = 0; s < 4; ++s)
                xr[cur ^ 1][s] = *(const uint4*)(xwbase + (c + 1) * 128 + s * 32);
            #pragma unroll
            for (int p = 0; p < 4; ++p) {
                const int row = 4 * p + drow;
                const int j   = (l & 15) ^ (row & 15);
                gld_lds16_nt(qwbase + (size_t)row * QROW + (c + 1) * CH32 + j * 4,
                             &qbuf[w][cur ^ 1][p * 256]);
            }
            // retire chunk c's 8 ops; leave chunk c+1's 8 in flight
            asm volatile("s_waitcnt vmcnt(8)" ::: "memory");
        } else {
            asm volatile("s_waitcnt vmcnt(0)" ::: "memory");
        }
        __builtin_amdgcn_sched_barrier(0);   // rule #18: pin ds_reads below wait

        const char* wb = (const char*)qbuf[w][cur];
        #pragma unroll
        for (int s = 0; s < 4; ++s) {
            // read slot j0 = s*4+g of row r, stored at slot j0^r (2-way = free)
            const int4 q = *(const int4*)(wb + r * 256 + ((((s << 2) + g) ^ r) << 4));
            // nibble e=2m lo / e=2m+1 hi of byte m; signed; exact in bf16
            uint4 ub = {
                bf16pk((float)((q.x << 28) >> 28), (float)((q.x << 24) >> 28)),
                bf16pk((float)((q.y << 28) >> 28), (float)((q.y << 24) >> 28)),
                bf16pk((float)((q.z << 28) >> 28), (float)((q.z << 24) >> 28)),
                bf16pk((float)((q.w << 28) >> 28), (float)((q.w << 24) >> 28))
            };
            short8v bfrag = __builtin_bit_cast(short8v, ub);
            short8v afrag = __builtin_bit_cast(short8v, xr[cur][s]);
            acc = __builtin_amdgcn_mfma_f32_16x16x32_bf16(afrag, bfrag, acc, 0, 0, 0);
        }
    }

    // ---- cross-wave K reduction; D map: col=lane&15 (out), row=(lane>>4)*4+j
    red[w][g * 4 + 0][r] = acc[0];
    red[w][g * 4 + 1][r] = acc[1];
    red[w][g * 4 + 2][r] = acc[2];
    red[w][g * 4 + 3][r] = acc[3];
    __syncthreads();

    if (t < 256) {
        const int b = t >> 4;            // batch
        const int o = t & 15;            // out within tile
        const int oc = obase + o;
        float v = 0.f;
        #pragma unroll
        for (int i = 0; i < 8; ++i) v += red[i][b][o];
        out[b * OUT_N + oc] = v * scale[oc >> 7] + bias[oc];
    }
}

extern "C" void kernel_launch(void* const* d_in, const int* in_sizes, int n_in,
                              void* d_out, int out_size, void* d_ws, size_t ws_size,
                              hipStream_t stream) {
    (void)in_sizes; (void)n_in; (void)ws_size; (void)out_size;
    const float* x     = (const float*)d_in[0];
    const int*   qp    = (const int*)d_in[1];
    const float* scale = (const float*)d_in[2];
    const float* bias  = (const float*)d_in[3];
    float*       out   = (float*)d_out;
    unsigned short* xb = (unsigned short*)d_ws;    // 256 KB bf16 x

    xconv_kernel<<<dim3((16 * IN_N) / (256 * 4)), dim3(256), 0, stream>>>(x, xb);
    qlin_mfma_kernel<<<dim3(OUT_N / 16), dim3(512), 0, stream>>>(qp, xb, scale, bias, out);
}

// Round 12
// 33.554 us; speedup vs baseline: 1.2218x; 1.0742x over previous
//
#include <hip/hip_runtime.h>
#include <hip/hip_bf16.h>

#define OUT_N 8192
#define IN_N  8192
#define QROW  (IN_N / 2)     // 4096 int32 per out row (one widened byte each)
#define NCH   4              // k sub-chunks per wave
#define CH32  128            // int32 per row per chunk -> 512-B contiguous granule
#define STEPS 8              // MFMA k-steps per chunk (256 elems / 32)

typedef __attribute__((ext_vector_type(8))) short short8v;  // 8 bf16
typedef __attribute__((ext_vector_type(4))) float f32x4;

__device__ __forceinline__ unsigned int bf16pk(float a, float b) {
    __hip_bfloat162 h = __float22bfloat162_rn(make_float2(a, b));
    unsigned int u;
    __builtin_memcpy(&u, &h, 4);
    return u;
}

// async global->LDS, 16B/lane; LDS dest = wave-uniform base + lane*16 (HW rule)
__device__ __forceinline__ void gld_lds16(const int* gsrc, int* ldst_base) {
    __builtin_amdgcn_global_load_lds(
        (const __attribute__((address_space(1))) void*)gsrc,
        (__attribute__((address_space(3))) void*)ldst_base, 16, 0, 0);
}

// Pre-pass: x fp32 -> bf16 row-major [16][8192] in d_ws (256 KB, L2/L3-hot).
__global__ __launch_bounds__(256) void xconv_kernel(
    const float* __restrict__ x, unsigned short* __restrict__ xb)
{
    int i = (blockIdx.x * 256 + threadIdx.x) * 4;
    float4 v = *(const float4*)(x + i);
    uint2 u = { bf16pk(v.x, v.y), bf16pk(v.z, v.w) };
    *(uint2*)(xb + i) = u;
}

// Wave-private single-buffer engine, 512-B DRAM granules at 16 waves/CU.
// One block = one 16-out-row tile; 8 waves split K 8 ways. Each wave stages
// its full 8KB chunk slice (16 rows x 512 B contiguous) via 8 DMAs of
// 2 rows x 512 B, then vmcnt(0) (wave-private drain — no block barrier, other
// waves keep HBM fed; service time 13k cyc >> compute 700 cyc so the single
// buffer costs nothing while doubling the DRAM granule vs R6).
// LDS swizzle: logical 16B slot j of row r stored at j ^ ((r&7)<<2); DMA
// source pre-swizzled with the same involution (LDS dest linear, m173).
__global__ __launch_bounds__(512, 4) void qlin_mfma_kernel(
    const int*            __restrict__ qp,
    const unsigned short* __restrict__ xb,
    const float*          __restrict__ scale,
    const float*          __restrict__ bias,
    float*                __restrict__ out)
{
    __shared__ int   qbuf[8][16][CH32];   // 8 waves x 8 KB = 64 KB single buffer
    __shared__ float red[8][16][17];      // 8.7 KB reduction scratch

    const int t = threadIdx.x;
    const int w = t >> 6;            // wave id -> k range [w*1024, +1024) elems
    const int l = t & 63;
    const int g = l >> 4;            // lane group 0..3
    const int r = l & 15;            // A: batch row, B: out row within tile
    const int tile = blockIdx.x;
    const int obase = tile * 16;

    // wave-uniform q base for this wave's k-range (int32 units)
    const int* qwbase = qp + (size_t)obase * QROW + w * (QROW / 8);
    const int dR   = l >> 5;                  // DMA row sub-index (0/1)
    const int dsl  = l & 31;                  // physical 16B slot this lane fills
    // x bf16 base: elem = r*IN_N + w*1024 + c*256 + s*32 + g*8
    const unsigned short* xwbase = xb + (size_t)r * IN_N + w * (IN_N / 8) + g * 8;

    f32x4 acc = {0.f, 0.f, 0.f, 0.f};
    uint4 xr[STEPS];                 // x fragments for current chunk (32 VGPR)

    #pragma unroll   // full unroll: static indices + static vmcnt imms
    for (int c = 0; c < NCH; ++c) {
        // ---- stage chunk c: 8 q-DMAs (2 rows x 512 B contiguous each)
        #pragma unroll
        for (int p = 0; p < 8; ++p) {
            const int R = 2 * p + dR;
            const int j = dsl ^ ((R & 7) << 2);   // pre-swizzled source slot
            gld_lds16(qwbase + (size_t)R * QROW + c * CH32 + j * 4,
                      &qbuf[w][2 * p][0]);
        }
        // x loads for chunk c (L2-hot, latency hidden under q service)
        #pragma unroll
        for (int s = 0; s < STEPS; ++s)
            xr[s] = *(const uint4*)(xwbase + c * 256 + s * 32);

        asm volatile("s_waitcnt vmcnt(0)" ::: "memory");   // wave-private drain
        __builtin_amdgcn_sched_barrier(0);   // rule #18: pin ds_reads below wait

        const char* wb = (const char*)&qbuf[w][0][0];
        #pragma unroll
        for (int s = 0; s < STEPS; ++s) {
            // logical slot j0 = s*4+g of row r lives at physical j0^((r&7)<<2)
            const int4 q = *(const int4*)(wb + r * 512 + ((((s << 2) + g) ^ ((r & 7) << 2)) << 4));
            // nibble e=2m lo / e=2m+1 hi of byte m; signed; exact in bf16
            uint4 ub = {
                bf16pk((float)((q.x << 28) >> 28), (float)((q.x << 24) >> 28)),
                bf16pk((float)((q.y << 28) >> 28), (float)((q.y << 24) >> 28)),
                bf16pk((float)((q.z << 28) >> 28), (float)((q.z << 24) >> 28)),
                bf16pk((float)((q.w << 28) >> 28), (float)((q.w << 24) >> 28))
            };
            short8v bfrag = __builtin_bit_cast(short8v, ub);
            short8v afrag = __builtin_bit_cast(short8v, xr[s]);
            acc = __builtin_amdgcn_mfma_f32_16x16x32_bf16(afrag, bfrag, acc, 0, 0, 0);
        }
        // next chunk's DMAs overwrite qbuf[w] — safe: same wave, reads done
        __builtin_amdgcn_sched_barrier(0);
    }

    // ---- cross-wave K reduction; D map: col=lane&15 (out), row=(lane>>4)*4+j
    red[w][g * 4 + 0][r] = acc[0];
    red[w][g * 4 + 1][r] = acc[1];
    red[w][g * 4 + 2][r] = acc[2];
    red[w][g * 4 + 3][r] = acc[3];
    __syncthreads();

    if (t < 256) {
        const int b = t >> 4;            // batch
        const int o = t & 15;            // out within tile
        const int oc = obase + o;
        float v = 0.f;
        #pragma unroll
        for (int i = 0; i < 8; ++i) v += red[i][b][o];
        out[b * OUT_N + oc] = v * scale[oc >> 7] + bias[oc];
    }
}

extern "C" void kernel_launch(void* const* d_in, const int* in_sizes, int n_in,
                              void* d_out, int out_size, void* d_ws, size_t ws_size,
                              hipStream_t stream) {
    (void)in_sizes; (void)n_in; (void)ws_size; (void)out_size;
    const float* x     = (const float*)d_in[0];
    const int*   qp    = (const int*)d_in[1];
    const float* scale = (const float*)d_in[2];
    const float* bias  = (const float*)d_in[3];
    float*       out   = (float*)d_out;
    unsigned short* xb = (unsigned short*)d_ws;    // 256 KB bf16 x

    xconv_kernel<<<dim3((16 * IN_N) / (256 * 4)), dim3(256), 0, stream>>>(x, xb);
    qlin_mfma_kernel<<<dim3(OUT_N / 16), dim3(512), 0, stream>>>(qp, xb, scale, bias, out);
}

// Round 13
// 33.038 us; speedup vs baseline: 1.2409x; 1.0156x over previous
//
#include <hip/hip_runtime.h>
#include <hip/hip_bf16.h>

#define OUT_N 8192
#define IN_N  8192
#define QROW  (IN_N / 2)     // 4096 int32 per out row (one widened byte each)
#define NCH   8              // k sub-chunks per wave
#define CH32  64             // int32 per row per sub-chunk (per wave)

typedef __attribute__((ext_vector_type(8))) short short8v;  // 8 bf16
typedef __attribute__((ext_vector_type(4))) float f32x4;

__device__ __forceinline__ unsigned int bf16pk(float a, float b) {
    __hip_bfloat162 h = __float22bfloat162_rn(make_float2(a, b));
    unsigned int u;
    __builtin_memcpy(&u, &h, 4);
    return u;
}

// async global->LDS, 16B/lane; LDS dest = wave-uniform base + lane*16 (HW rule)
__device__ __forceinline__ void gld_lds16(const int* gsrc, int* ldst_base) {
    __builtin_amdgcn_global_load_lds(
        (const __attribute__((address_space(1))) void*)gsrc,
        (__attribute__((address_space(3))) void*)ldst_base, 16, 0, 0);
}

// Pre-pass: x fp32 -> bf16 row-major [16][8192] in d_ws (256 KB, L2/L3-hot).
__global__ __launch_bounds__(256) void xconv_kernel(
    const float* __restrict__ x, unsigned short* __restrict__ xb)
{
    int i = (blockIdx.x * 256 + threadIdx.x) * 4;
    float4 v = *(const float4*)(x + i);
    uint2 u = { bf16pk(v.x, v.y), bf16pk(v.z, v.w) };
    *(uint2*)(xb + i) = u;
}

// R6 engine (proven best: 32.9 us) + T1 XCD-chunked block swizzle.
// One block = one 16-out-row tile; 8 waves split K 8 ways. WAVE-PRIVATE q
// staging: each wave DMAs the exact 4KB slice it consumes (16 rows x 256B of
// its k-range) into its own LDS double buffer -> NO block barrier in the main
// loop; counted vmcnt(8) keeps next chunk's 8 vmem ops in flight (T4),
// vmcnt(0) only on the last chunk.
// T1: grid 512 = 8 XCDs x 64 -> tile=(b&7)*64+(b>>3) gives each XCD one
// contiguous 16-MB q region (HBM page locality for the miss streams).
// LDS read swizzle: slot j of row R stored at j^R (global DMA source
// pre-swizzled, LDS dest linear — m173).
__global__ __launch_bounds__(512, 4) void qlin_mfma_kernel(
    const int*            __restrict__ qp,
    const unsigned short* __restrict__ xb,
    const float*          __restrict__ scale,
    const float*          __restrict__ bias,
    float*                __restrict__ out)
{
    __shared__ int   qbuf[8][2][16 * CH32];   // 8 waves x 2 x 4KB = 64 KB
    __shared__ float red[8][16][17];          // 8.7 KB reduction scratch

    const int t = threadIdx.x;
    const int w = t >> 6;            // wave id -> k range [w*1024, +1024) elems
    const int l = t & 63;
    const int g = l >> 4;            // lane group 0..3
    const int r = l & 15;            // A: batch row, B: out row within tile
    const int bid  = blockIdx.x;
    const int tile = (bid & 7) * 64 + (bid >> 3);   // T1 chunked XCD swizzle
    const int obase = tile * 16;

    // wave-uniform q base for this wave's k-range (int32 units)
    const int* qwbase = qp + (size_t)obase * QROW + w * (QROW / 8);
    const int drow = l >> 4;                      // DMA row sub-index (+4p)
    // x bf16 base: elem = r*IN_N + w*1024 + c*128 + s*32 + g*8
    const unsigned short* xwbase = xb + (size_t)r * IN_N + w * (IN_N / 8) + g * 8;

    f32x4 acc = {0.f, 0.f, 0.f, 0.f};
    uint4 xr[2][4];

    // ---- prologue: chunk 0 (4 x-loads then 4 DMAs = 8 vmem ops)
    #pragma unroll
    for (int s = 0; s < 4; ++s)
        xr[0][s] = *(const uint4*)(xwbase + s * 32);
    #pragma unroll
    for (int p = 0; p < 4; ++p) {
        const int row = 4 * p + drow;
        const int j   = (l & 15) ^ (row & 15);    // pre-swizzled source slot
        gld_lds16(qwbase + (size_t)row * QROW + j * 4, &qbuf[w][0][p * 256]);
    }

    #pragma unroll   // full unroll: static buffer indices + static vmcnt imms
    for (int c = 0; c < NCH; ++c) {
        const int cur = c & 1;

        if (c + 1 < NCH) {
            // issue next chunk: x loads FIRST (L2, retire first), then DMAs
            #pragma unroll
            for (int s = 0; s < 4; ++s)
                xr[cur ^ 1][s] = *(const uint4*)(xwbase + (c + 1) * 128 + s * 32);
            #pragma unroll
            for (int p = 0; p < 4; ++p) {
                const int row = 4 * p + drow;
                const int j   = (l & 15) ^ (row & 15);
                gld_lds16(qwbase + (size_t)row * QROW + (c + 1) * CH32 + j * 4,
                          &qbuf[w][cur ^ 1][p * 256]);
            }
            // retire chunk c's 8 ops; leave chunk c+1's 8 in flight
            asm volatile("s_waitcnt vmcnt(8)" ::: "memory");
        } else {
            asm volatile("s_waitcnt vmcnt(0)" ::: "memory");
        }
        __builtin_amdgcn_sched_barrier(0);   // rule #18: pin ds_reads below wait

        const char* wb = (const char*)qbuf[w][cur];
        #pragma unroll
        for (int s = 0; s < 4; ++s) {
            // read slot j0 = s*4+g of row r, stored at slot j0^r (2-way = free)
            const int4 q = *(const int4*)(wb + r * 256 + ((((s << 2) + g) ^ r) << 4));
            // nibble e=2m lo / e=2m+1 hi of byte m; signed; exact in bf16
            uint4 ub = {
                bf16pk((float)((q.x << 28) >> 28), (float)((q.x << 24) >> 28)),
                bf16pk((float)((q.y << 28) >> 28), (float)((q.y << 24) >> 28)),
                bf16pk((float)((q.z << 28) >> 28), (float)((q.z << 24) >> 28)),
                bf16pk((float)((q.w << 28) >> 28), (float)((q.w << 24) >> 28))
            };
            short8v bfrag = __builtin_bit_cast(short8v, ub);
            short8v afrag = __builtin_bit_cast(short8v, xr[cur][s]);
            acc = __builtin_amdgcn_mfma_f32_16x16x32_bf16(afrag, bfrag, acc, 0, 0, 0);
        }
    }

    // ---- cross-wave K reduction; D map: col=lane&15 (out), row=(lane>>4)*4+j
    red[w][g * 4 + 0][r] = acc[0];
    red[w][g * 4 + 1][r] = acc[1];
    red[w][g * 4 + 2][r] = acc[2];
    red[w][g * 4 + 3][r] = acc[3];
    __syncthreads();

    if (t < 256) {
        const int b = t >> 4;            // batch
        const int o = t & 15;            // out within tile
        const int oc = obase + o;
        float v = 0.f;
        #pragma unroll
        for (int i = 0; i < 8; ++i) v += red[i][b][o];
        out[b * OUT_N + oc] = v * scale[oc >> 7] + bias[oc];
    }
}

extern "C" void kernel_launch(void* const* d_in, const int* in_sizes, int n_in,
                              void* d_out, int out_size, void* d_ws, size_t ws_size,
                              hipStream_t stream) {
    (void)in_sizes; (void)n_in; (void)ws_size; (void)out_size;
    const float* x     = (const float*)d_in[0];
    const int*   qp    = (const int*)d_in[1];
    const float* scale = (const float*)d_in[2];
    const float* bias  = (const float*)d_in[3];
    float*       out   = (float*)d_out;
    unsigned short* xb = (unsigned short*)d_ws;    // 256 KB bf16 x

    xconv_kernel<<<dim3((16 * IN_N) / (256 * 4)), dim3(256), 0, stream>>>(x, xb);
    qlin_mfma_kernel<<<dim3(OUT_N / 16), dim3(512), 0, stream>>>(qp, xb, scale, bias, out);
}

// Round 14
// 32.668 us; speedup vs baseline: 1.2549x; 1.0113x over previous
//
#include <hip/hip_runtime.h>
#include <hip/hip_bf16.h>

#define OUT_N 8192
#define IN_N  8192
#define QROW  (IN_N / 2)     // 4096 int32 per out row (one widened byte each)
#define NCH   8              // k sub-chunks per wave
#define CH32  64             // int32 per row per sub-chunk (per wave)

typedef __attribute__((ext_vector_type(8))) short short8v;  // 8 bf16
typedef __attribute__((ext_vector_type(4))) float f32x4;

__device__ __forceinline__ unsigned int bf16pk(float a, float b) {
    __hip_bfloat162 h = __float22bfloat162_rn(make_float2(a, b));
    unsigned int u;
    __builtin_memcpy(&u, &h, 4);
    return u;
}

// async global->LDS, 16B/lane; LDS dest = wave-uniform base + lane*16 (HW rule)
__device__ __forceinline__ void gld_lds16(const int* gsrc, int* ldst_base) {
    __builtin_amdgcn_global_load_lds(
        (const __attribute__((address_space(1))) void*)gsrc,
        (__attribute__((address_space(3))) void*)ldst_base, 16, 0, 0);
}

// Pre-pass: x fp32 -> bf16 row-major [16][8192] in d_ws (256 KB, L2/L3-hot).
__global__ __launch_bounds__(256) void xconv_kernel(
    const float* __restrict__ x, unsigned short* __restrict__ xb)
{
    int i = (blockIdx.x * 256 + threadIdx.x) * 4;
    float4 v = *(const float4*)(x + i);
    uint2 u = { bf16pk(v.x, v.y), bf16pk(v.z, v.w) };
    *(uint2*)(xb + i) = u;
}

// R6 engine (proven best: 32.9 us) + per-tile chunk-phase rotation.
// One block = one 16-out-row tile; 8 waves split K 8 ways. WAVE-PRIVATE q
// staging: each wave DMAs the exact 4KB slice it consumes (16 rows x 256B of
// its k-range) into its own LDS double buffer -> NO block barrier in the main
// loop; counted vmcnt(8) keeps next chunk's 8 vmem ops in flight (T4),
// vmcnt(0) only on the last chunk.
// NEW: chunk schedule rotated by ph = tile & 7 (K-sum order is free) so
// concurrent tiles sit at different 256-B column phases of their 16-KB-
// aligned rows -> decorrelates HBM channel access device-wide.
// LDS read swizzle: slot j of row R stored at j^R (global DMA source
// pre-swizzled, LDS dest linear — m173).
__global__ __launch_bounds__(512, 4) void qlin_mfma_kernel(
    const int*            __restrict__ qp,
    const unsigned short* __restrict__ xb,
    const float*          __restrict__ scale,
    const float*          __restrict__ bias,
    float*                __restrict__ out)
{
    __shared__ int   qbuf[8][2][16 * CH32];   // 8 waves x 2 x 4KB = 64 KB
    __shared__ float red[8][16][17];          // 8.7 KB reduction scratch

    const int t = threadIdx.x;
    const int w = t >> 6;            // wave id -> k range [w*1024, +1024) elems
    const int l = t & 63;
    const int g = l >> 4;            // lane group 0..3
    const int r = l & 15;            // A: batch row, B: out row within tile
    const int tile = blockIdx.x;
    const int obase = tile * 16;
    const int ph = tile & 7;         // chunk-phase rotation for this tile

    // wave-uniform q base for this wave's k-range (int32 units)
    const int* qwbase = qp + (size_t)obase * QROW + w * (QROW / 8);
    const int drow = l >> 4;                      // DMA row sub-index (+4p)
    // x bf16 base: elem = r*IN_N + w*1024 + cc*128 + s*32 + g*8
    const unsigned short* xwbase = xb + (size_t)r * IN_N + w * (IN_N / 8) + g * 8;

    f32x4 acc = {0.f, 0.f, 0.f, 0.f};
    uint4 xr[2][4];

    // ---- prologue: chunk phase ph (4 x-loads then 4 DMAs = 8 vmem ops)
    #pragma unroll
    for (int s = 0; s < 4; ++s)
        xr[0][s] = *(const uint4*)(xwbase + ph * 128 + s * 32);
    #pragma unroll
    for (int p = 0; p < 4; ++p) {
        const int row = 4 * p + drow;
        const int j   = (l & 15) ^ (row & 15);    // pre-swizzled source slot
        gld_lds16(qwbase + (size_t)row * QROW + ph * CH32 + j * 4,
                  &qbuf[w][0][p * 256]);
    }

    #pragma unroll   // full unroll: static buffer indices + static vmcnt imms
    for (int c0 = 0; c0 < NCH; ++c0) {
        const int cur = c0 & 1;

        if (c0 + 1 < NCH) {
            const int ccn = (c0 + 1 + ph) & 7;    // next chunk (rotated)
            // issue next chunk: x loads FIRST (L2, retire first), then DMAs
            #pragma unroll
            for (int s = 0; s < 4; ++s)
                xr[cur ^ 1][s] = *(const uint4*)(xwbase + ccn * 128 + s * 32);
            #pragma unroll
            for (int p = 0; p < 4; ++p) {
                const int row = 4 * p + drow;
                const int j   = (l & 15) ^ (row & 15);
                gld_lds16(qwbase + (size_t)row * QROW + ccn * CH32 + j * 4,
                          &qbuf[w][cur ^ 1][p * 256]);
            }
            // retire chunk c0's 8 ops; leave chunk c0+1's 8 in flight
            asm volatile("s_waitcnt vmcnt(8)" ::: "memory");
        } else {
            asm volatile("s_waitcnt vmcnt(0)" ::: "memory");
        }
        __builtin_amdgcn_sched_barrier(0);   // rule #18: pin ds_reads below wait

        const char* wb = (const char*)qbuf[w][cur];
        #pragma unroll
        for (int s = 0; s < 4; ++s) {
            // read slot j0 = s*4+g of row r, stored at slot j0^r (2-way = free)
            const int4 q = *(const int4*)(wb + r * 256 + ((((s << 2) + g) ^ r) << 4));
            // nibble e=2m lo / e=2m+1 hi of byte m; signed; exact in bf16
            uint4 ub = {
                bf16pk((float)((q.x << 28) >> 28), (float)((q.x << 24) >> 28)),
                bf16pk((float)((q.y << 28) >> 28), (float)((q.y << 24) >> 28)),
                bf16pk((float)((q.z << 28) >> 28), (float)((q.z << 24) >> 28)),
                bf16pk((float)((q.w << 28) >> 28), (float)((q.w << 24) >> 28))
            };
            short8v bfrag = __builtin_bit_cast(short8v, ub);
            short8v afrag = __builtin_bit_cast(short8v, xr[cur][s]);
            acc = __builtin_amdgcn_mfma_f32_16x16x32_bf16(afrag, bfrag, acc, 0, 0, 0);
        }
    }

    // ---- cross-wave K reduction; D map: col=lane&15 (out), row=(lane>>4)*4+j
    red[w][g * 4 + 0][r] = acc[0];
    red[w][g * 4 + 1][r] = acc[1];
    red[w][g * 4 + 2][r] = acc[2];
    red[w][g * 4 + 3][r] = acc[3];
    __syncthreads();

    if (t < 256) {
        const int b = t >> 4;            // batch
        const int o = t & 15;            // out within tile
        const int oc = obase + o;
        float v = 0.f;
        #pragma unroll
        for (int i = 0; i < 8; ++i) v += red[i][b][o];
        out[b * OUT_N + oc] = v * scale[oc >> 7] + bias[oc];
    }
}

extern "C" void kernel_launch(void* const* d_in, const int* in_sizes, int n_in,
                              void* d_out, int out_size, void* d_ws, size_t ws_size,
                              hipStream_t stream) {
    (void)in_sizes; (void)n_in; (void)ws_size; (void)out_size;
    const float* x     = (const float*)d_in[0];
    const int*   qp    = (const int*)d_in[1];
    const float* scale = (const float*)d_in[2];
    const float* bias  = (const float*)d_in[3];
    float*       out   = (float*)d_out;
    unsigned short* xb = (unsigned short*)d_ws;    // 256 KB bf16 x

    xconv_kernel<<<dim3((16 * IN_N) / (256 * 4)), dim3(256), 0, stream>>>(x, xb);
    qlin_mfma_kernel<<<dim3(OUT_N / 16), dim3(512), 0, stream>>>(qp, xb, scale, bias, out);
}

// Round 15
// 30.789 us; speedup vs baseline: 1.3315x; 1.0611x over previous
//
#include <hip/hip_runtime.h>
#include <hip/hip_bf16.h>

#define OUT_N 8192
#define IN_N  8192
#define QROW  (IN_N / 2)     // 4096 int32 per out row (one widened byte each)
#define NCH   8              // k sub-chunks per wave
#define CH32  64             // int32 per row per sub-chunk (per wave)

typedef __attribute__((ext_vector_type(8))) short short8v;  // 8 bf16
typedef __attribute__((ext_vector_type(4))) float f32x4;

__device__ __forceinline__ unsigned int bf16pk(float a, float b) {
    __hip_bfloat162 h = __float22bfloat162_rn(make_float2(a, b));
    unsigned int u;
    __builtin_memcpy(&u, &h, 4);
    return u;
}

// async global->LDS, 16B/lane; LDS dest = wave-uniform base + lane*16 (HW rule)
__device__ __forceinline__ void gld_lds16(const int* gsrc, int* ldst_base) {
    __builtin_amdgcn_global_load_lds(
        (const __attribute__((address_space(1))) void*)gsrc,
        (__attribute__((address_space(3))) void*)ldst_base, 16, 0, 0);
}

// Pre-pass: x fp32 -> bf16 PERMUTED to the exact main-kernel consume order:
// uint4 slot [(w*32 + c*4 + s)*64 + l] = bf16x8 of x[row=l&15][w*1024+c*128+
// s*32+(l>>4)*8 .. +8]. Main-kernel x loads become wave-uniform base + l*16B
// -> fully contiguous 1-KB per instr (removes 2.1M scattered 64-B txns).
__global__ __launch_bounds__(256) void xconv_kernel(
    const float* __restrict__ x, uint4* __restrict__ xb2)
{
    const int tid = blockIdx.x * 256 + threadIdx.x;   // 16384 uint4 outputs
    const int l   = tid & 63;
    const int scs = tid >> 6;        // 0..255
    const int s   = scs & 3;
    const int c   = (scs >> 2) & 7;
    const int w   = scs >> 5;
    const int r   = l & 15;
    const int g   = l >> 4;
    const float* src = x + (size_t)r * IN_N + w * 1024 + c * 128 + s * 32 + g * 8;
    float4 a = *(const float4*)src;
    float4 b = *(const float4*)(src + 4);
    uint4 u = { bf16pk(a.x, a.y), bf16pk(a.z, a.w),
                bf16pk(b.x, b.y), bf16pk(b.z, b.w) };
    xb2[tid] = u;
}

// R14 engine (best: 32.7 us) + permuted-x contiguous loads.
// One block = one 16-out-row tile; 8 waves split K 8 ways. WAVE-PRIVATE q
// staging: each wave DMAs the exact 4KB slice it consumes (16 rows x 256B)
// into its own LDS double buffer -> NO block barrier in the main loop;
// counted vmcnt(8) keeps next chunk's 8 vmem ops in flight, vmcnt(0) only on
// the last chunk. Chunk schedule rotated by ph = tile & 7 (K-order free).
// LDS read swizzle: slot j of row R stored at j^R (DMA source pre-swizzled).
__global__ __launch_bounds__(512, 4) void qlin_mfma_kernel(
    const int*   __restrict__ qp,
    const uint4* __restrict__ xb2,
    const float* __restrict__ scale,
    const float* __restrict__ bias,
    float*       __restrict__ out)
{
    __shared__ int   qbuf[8][2][16 * CH32];   // 8 waves x 2 x 4KB = 64 KB
    __shared__ float red[8][16][17];          // 8.7 KB reduction scratch

    const int t = threadIdx.x;
    const int w = t >> 6;            // wave id -> k range [w*1024, +1024) elems
    const int l = t & 63;
    const int g = l >> 4;            // lane group 0..3
    const int r = l & 15;            // A: batch row, B: out row within tile
    const int tile = blockIdx.x;
    const int obase = tile * 16;
    const int ph = tile & 7;         // chunk-phase rotation for this tile

    // wave-uniform q base for this wave's k-range (int32 units)
    const int* qwbase = qp + (size_t)obase * QROW + w * (QROW / 8);
    const int drow = l >> 4;                      // DMA row sub-index (+4p)
    // permuted x base: slot (w*32 + c*4 + s)*64 + l
    const uint4* xwbase = xb2 + (w << 11) + l;    // + c*256 + s*64

    f32x4 acc = {0.f, 0.f, 0.f, 0.f};
    uint4 xr[2][4];

    // ---- prologue: chunk phase ph (4 x-loads then 4 DMAs = 8 vmem ops)
    #pragma unroll
    for (int s = 0; s < 4; ++s)
        xr[0][s] = xwbase[ph * 256 + s * 64];
    #pragma unroll
    for (int p = 0; p < 4; ++p) {
        const int row = 4 * p + drow;
        const int j   = (l & 15) ^ (row & 15);    // pre-swizzled source slot
        gld_lds16(qwbase + (size_t)row * QROW + ph * CH32 + j * 4,
                  &qbuf[w][0][p * 256]);
    }

    #pragma unroll   // full unroll: static buffer indices + static vmcnt imms
    for (int c0 = 0; c0 < NCH; ++c0) {
        const int cur = c0 & 1;

        if (c0 + 1 < NCH) {
            const int ccn = (c0 + 1 + ph) & 7;    // next chunk (rotated)
            // issue next chunk: x loads FIRST (L2, retire first), then DMAs
            #pragma unroll
            for (int s = 0; s < 4; ++s)
                xr[cur ^ 1][s] = xwbase[ccn * 256 + s * 64];
            #pragma unroll
            for (int p = 0; p < 4; ++p) {
                const int row = 4 * p + drow;
                const int j   = (l & 15) ^ (row & 15);
                gld_lds16(qwbase + (size_t)row * QROW + ccn * CH32 + j * 4,
                          &qbuf[w][cur ^ 1][p * 256]);
            }
            // retire chunk c0's 8 ops; leave chunk c0+1's 8 in flight
            asm volatile("s_waitcnt vmcnt(8)" ::: "memory");
        } else {
            asm volatile("s_waitcnt vmcnt(0)" ::: "memory");
        }
        __builtin_amdgcn_sched_barrier(0);   // rule #18: pin ds_reads below wait

        const char* wb = (const char*)qbuf[w][cur];
        #pragma unroll
        for (int s = 0; s < 4; ++s) {
            // read slot j0 = s*4+g of row r, stored at slot j0^r (2-way = free)
            const int4 q = *(const int4*)(wb + r * 256 + ((((s << 2) + g) ^ r) << 4));
            // nibble e=2m lo / e=2m+1 hi of byte m; signed; exact in bf16
            uint4 ub = {
                bf16pk((float)((q.x << 28) >> 28), (float)((q.x << 24) >> 28)),
                bf16pk((float)((q.y << 28) >> 28), (float)((q.y << 24) >> 28)),
                bf16pk((float)((q.z << 28) >> 28), (float)((q.z << 24) >> 28)),
                bf16pk((float)((q.w << 28) >> 28), (float)((q.w << 24) >> 28))
            };
            short8v bfrag = __builtin_bit_cast(short8v, ub);
            short8v afrag = __builtin_bit_cast(short8v, xr[cur][s]);
            acc = __builtin_amdgcn_mfma_f32_16x16x32_bf16(afrag, bfrag, acc, 0, 0, 0);
        }
    }

    // ---- cross-wave K reduction; D map: col=lane&15 (out), row=(lane>>4)*4+j
    red[w][g * 4 + 0][r] = acc[0];
    red[w][g * 4 + 1][r] = acc[1];
    red[w][g * 4 + 2][r] = acc[2];
    red[w][g * 4 + 3][r] = acc[3];
    __syncthreads();

    if (t < 256) {
        const int b = t >> 4;            // batch
        const int o = t & 15;            // out within tile
        const int oc = obase + o;
        float v = 0.f;
        #pragma unroll
        for (int i = 0; i < 8; ++i) v += red[i][b][o];
        out[b * OUT_N + oc] = v * scale[oc >> 7] + bias[oc];
    }
}

extern "C" void kernel_launch(void* const* d_in, const int* in_sizes, int n_in,
                              void* d_out, int out_size, void* d_ws, size_t ws_size,
                              hipStream_t stream) {
    (void)in_sizes; (void)n_in; (void)ws_size; (void)out_size;
    const float* x     = (const float*)d_in[0];
    const int*   qp    = (const int*)d_in[1];
    const float* scale = (const float*)d_in[2];
    const float* bias  = (const float*)d_in[3];
    float*       out   = (float*)d_out;
    uint4*       xb2   = (uint4*)d_ws;     // 256 KB permuted bf16 x

    xconv_kernel<<<dim3(64), dim3(256), 0, stream>>>(x, xb2);
    qlin_mfma_kernel<<<dim3(OUT_N / 16), dim3(512), 0, stream>>>(qp, xb2, scale, bias, out);
}